// Round 1
// baseline (265.690 us; speedup 1.0000x reference)
//
#include <hip/hip_runtime.h>
#include <math.h>

// Problem constants: B=2, L=1024, D=512, H=8, h=64, K=H=8, EPS=1e-5
// Layouts: q/k/v/k_conv/v_conv stored as [B*H][L][64] (bh*65536 + l*64 + d)

// ---------------------------------------------------------------------------
// K1: fused QKV projection.  x[2048,512] @ W[512,512] (+bias)*scale, written
// into [B,H,L,h] layout.  grid (8 colTiles, 32 rowTiles, 3 weights), 256 thr.
// ---------------------------------------------------------------------------
__global__ __launch_bounds__(256) void k_qkv(
    const float* __restrict__ x,
    const float* __restrict__ wq, const float* __restrict__ bq,
    const float* __restrict__ wk, const float* __restrict__ bk,
    const float* __restrict__ wv, const float* __restrict__ bv,
    float* __restrict__ qo, float* __restrict__ ko, float* __restrict__ vo)
{
    const int tid = threadIdx.x;
    const int tx = tid & 15, ty = tid >> 4;
    const int col0 = blockIdx.x * 64;   // head = blockIdx.x (64 cols per head)
    const int row0 = blockIdx.y * 64;
    const float* w; const float* bias; float* dst; float scale;
    if (blockIdx.z == 0)      { w = wq; bias = bq; dst = qo; scale = 1.0f;   }
    else if (blockIdx.z == 1) { w = wk; bias = bk; dst = ko; scale = 0.125f; } // h^-0.5
    else                      { w = wv; bias = bv; dst = vo; scale = 1.0f;   }

    __shared__ float xs[64][17];
    __shared__ __align__(16) float wsb[16][68];
    float acc[4][4] = {};

    const float4* x4 = (const float4*)x;
    const float4* w4 = (const float4*)w;
    for (int k0 = 0; k0 < 512; k0 += 16) {
        {   // load x tile 64x16
            int r = tid >> 2, c4 = tid & 3;
            float4 t = x4[(size_t)(row0 + r) * 128 + (k0 >> 2) + c4];
            xs[r][c4*4+0] = t.x; xs[r][c4*4+1] = t.y;
            xs[r][c4*4+2] = t.z; xs[r][c4*4+3] = t.w;
        }
        {   // load w tile 16x64
            int r = tid >> 4, c4 = tid & 15;
            float4 t = w4[(size_t)(k0 + r) * 128 + (col0 >> 2) + c4];
            *(float4*)&wsb[r][c4*4] = t;
        }
        __syncthreads();
        #pragma unroll
        for (int kk = 0; kk < 16; ++kk) {
            float a[4];
            a[0] = xs[ty*4+0][kk]; a[1] = xs[ty*4+1][kk];
            a[2] = xs[ty*4+2][kk]; a[3] = xs[ty*4+3][kk];
            float4 b4 = *(const float4*)&wsb[kk][tx*4];
            float bb[4] = {b4.x, b4.y, b4.z, b4.w};
            #pragma unroll
            for (int ii = 0; ii < 4; ++ii)
                #pragma unroll
                for (int jj = 0; jj < 4; ++jj)
                    acc[ii][jj] += a[ii] * bb[jj];
        }
        __syncthreads();
    }

    const int b  = row0 >> 10;
    const int hd = blockIdx.x;
    const int dd = tx * 4;
    #pragma unroll
    for (int i = 0; i < 4; ++i) {
        int l = (row0 & 1023) + ty*4 + i;
        float4 o;
        o.x = (acc[i][0] + bias[col0+dd+0]) * scale;
        o.y = (acc[i][1] + bias[col0+dd+1]) * scale;
        o.z = (acc[i][2] + bias[col0+dd+2]) * scale;
        o.w = (acc[i][3] + bias[col0+dd+3]) * scale;
        *(float4*)&dst[(size_t)((b*8 + hd)*1024 + l) * 64 + dd] = o;
    }
}

// ---------------------------------------------------------------------------
// K2: causal Toeplitz conv.  y[t,d] = sum_{s<=t} f[t-s]*u[s,d], f per head.
// grid (16 tTiles, 32 = tensor*16 + bh), 256 thr.
// ---------------------------------------------------------------------------
__global__ __launch_bounds__(256) void k_conv(
    const float* __restrict__ sb,
    const float* __restrict__ kin, const float* __restrict__ vin,
    float* __restrict__ kc, float* __restrict__ vc)
{
    const int tid = threadIdx.x, tx = tid & 15, ty = tid >> 4;
    const int t0  = blockIdx.x * 64;
    const int tns = blockIdx.y >> 4;
    const int bh  = blockIdx.y & 15;
    const int hd  = bh & 7;
    const float* src = (tns ? vin : kin) + (size_t)bh * 65536;
    float*       dst = (tns ? vc  : kc ) + (size_t)bh * 65536;

    __shared__ __align__(16) float us[16][68];
    __shared__ float fwin[80];
    float acc[4][4] = {};

    const float4* s4 = (const float4*)src;
    for (int s0 = 0; s0 <= t0 + 63; s0 += 16) {
        const int base = t0 - s0 - 15;
        if (tid < 80) {
            int idx = base + tid;
            fwin[tid] = (idx >= 0 && idx < 1024) ? sb[idx*8 + hd] : 0.0f;
        }
        {
            int r = tid >> 4, c4 = tid & 15;
            float4 t = s4[(size_t)(s0 + r) * 16 + c4];
            *(float4*)&us[r][c4*4] = t;
        }
        __syncthreads();
        #pragma unroll
        for (int kk = 0; kk < 16; ++kk) {
            // f[t-s] with t = t0+ty*4+i, s = s0+kk -> fwin[(ty*4+i) + 15 - kk]
            float f[4];
            f[0] = fwin[ty*4+0 + 15 - kk];
            f[1] = fwin[ty*4+1 + 15 - kk];
            f[2] = fwin[ty*4+2 + 15 - kk];
            f[3] = fwin[ty*4+3 + 15 - kk];
            float4 u4 = *(const float4*)&us[kk][tx*4];
            float uu[4] = {u4.x, u4.y, u4.z, u4.w};
            #pragma unroll
            for (int ii = 0; ii < 4; ++ii)
                #pragma unroll
                for (int jj = 0; jj < 4; ++jj)
                    acc[ii][jj] += f[ii] * uu[jj];
        }
        __syncthreads();
    }
    #pragma unroll
    for (int i = 0; i < 4; ++i) {
        float4 o = { acc[i][0], acc[i][1], acc[i][2], acc[i][3] };
        *(float4*)&dst[(size_t)(t0 + ty*4 + i) * 64 + tx*4] = o;
    }
}

// ---------------------------------------------------------------------------
// K3: gate values.  T = K_conv @ Wg^T (T[l,m] = sum_n k[l,n]*wg[m*64+n]),
// logit[l] = sum_m v[l,m]*T[l,m] + wg_b; g = relu(logit)^2 + EPS.
// grid (16 lTiles, 16 bh), 256 thr.
// ---------------------------------------------------------------------------
__global__ __launch_bounds__(256) void k_gate(
    const float* __restrict__ kc, const float* __restrict__ vc,
    const float* __restrict__ wg_w, const float* __restrict__ wg_b,
    float* __restrict__ gl)
{
    const int tid = threadIdx.x, tx = tid & 15, ty = tid >> 4;
    const int l0 = blockIdx.x * 64;
    const int bh = blockIdx.y;
    const float* kb = kc + (size_t)bh * 65536;
    const float* vb = vc + (size_t)bh * 65536;

    __shared__ float ks[64][17];
    __shared__ __align__(16) float wsh[16][68];
    float acc[4][4] = {};
    const float4* k4 = (const float4*)kb;
    for (int n0 = 0; n0 < 64; n0 += 16) {
        {
            int r = tid >> 2, c4 = tid & 3;
            float4 t = k4[(size_t)(l0 + r) * 16 + (n0 >> 2) + c4];
            ks[r][c4*4+0]=t.x; ks[r][c4*4+1]=t.y; ks[r][c4*4+2]=t.z; ks[r][c4*4+3]=t.w;
        }
        for (int i = tid; i < 1024; i += 256) {   // wsh[nn][m] = wg[m*64 + n0+nn]
            int r = i >> 6, c = i & 63;
            wsh[r][c] = wg_w[c*64 + n0 + r];
        }
        __syncthreads();
        #pragma unroll
        for (int kk = 0; kk < 16; ++kk) {
            float a[4];
            a[0] = ks[ty*4+0][kk]; a[1] = ks[ty*4+1][kk];
            a[2] = ks[ty*4+2][kk]; a[3] = ks[ty*4+3][kk];
            float4 b4 = *(const float4*)&wsh[kk][tx*4];
            float bb[4] = {b4.x, b4.y, b4.z, b4.w};
            #pragma unroll
            for (int ii = 0; ii < 4; ++ii)
                #pragma unroll
                for (int jj = 0; jj < 4; ++jj)
                    acc[ii][jj] += a[ii] * bb[jj];
        }
        __syncthreads();
    }
    __shared__ float red[64][17];
    const float wgb = wg_b[0];
    const float4* v4p = (const float4*)vb;
    #pragma unroll
    for (int i = 0; i < 4; ++i) {
        int lr = ty*4 + i;
        float4 vv = v4p[(size_t)(l0 + lr) * 16 + tx];
        red[lr][tx] = acc[i][0]*vv.x + acc[i][1]*vv.y + acc[i][2]*vv.z + acc[i][3]*vv.w;
    }
    __syncthreads();
    if (tid < 64) {
        float s = 0.0f;
        #pragma unroll
        for (int t = 0; t < 16; ++t) s += red[tid][t];
        float logit = s + wgb;
        float r = fmaxf(logit, 0.0f);
        gl[bh*1024 + l0 + tid] = r*r + 1e-5f;
    }
}

// ---------------------------------------------------------------------------
// K4: scans.  G_l = prefix(g), r_l = 1/(G_l+EPS), c_j = suffix(r),
// w_j = g_j * c_j.  One block per bh, 256 thr x 4 elems.
// ---------------------------------------------------------------------------
__global__ __launch_bounds__(256) void k_scan(
    const float* __restrict__ gl, float* __restrict__ wgt)
{
    const int tid = threadIdx.x, bh = blockIdx.x;
    __shared__ float sbuf[256];
    const float4 g4 = ((const float4*)(gl + bh*1024))[tid];
    float g[4] = {g4.x, g4.y, g4.z, g4.w};
    float p[4];
    p[0]=g[0]; p[1]=p[0]+g[1]; p[2]=p[1]+g[2]; p[3]=p[2]+g[3];
    const float s = p[3];
    sbuf[tid] = s;
    __syncthreads();
    for (int off = 1; off < 256; off <<= 1) {
        float t = (tid >= off) ? sbuf[tid-off] : 0.0f;
        __syncthreads();
        sbuf[tid] += t;
        __syncthreads();
    }
    const float base = sbuf[tid] - s;     // exclusive prefix of g-partials
    float r[4], pr[4];
    #pragma unroll
    for (int u = 0; u < 4; ++u) r[u] = 1.0f / (base + p[u] + 1e-5f);
    pr[0]=r[0]; pr[1]=pr[0]+r[1]; pr[2]=pr[1]+r[2]; pr[3]=pr[2]+r[3];
    const float sr = pr[3];
    __syncthreads();
    sbuf[tid] = sr;
    __syncthreads();
    for (int off = 1; off < 256; off <<= 1) {
        float t = (tid >= off) ? sbuf[tid-off] : 0.0f;
        __syncthreads();
        sbuf[tid] += t;
        __syncthreads();
    }
    const float Rtot  = sbuf[255];
    const float baser = sbuf[tid] - sr;
    float4 o;
    o.x = g[0] * (Rtot - (baser + pr[0]) + r[0]);
    o.y = g[1] * (Rtot - (baser + pr[1]) + r[1]);
    o.z = g[2] * (Rtot - (baser + pr[2]) + r[2]);
    o.w = g[3] * (Rtot - (baser + pr[3]) + r[3]);
    ((float4*)(wgt + bh*1024))[tid] = o;
}

// ---------------------------------------------------------------------------
// K5: A_part[slc][bh] = sum_{j in slice} w_j * outer(v_conv[j], k_conv[j]).
// grid (16 bh, 4 slices), 256 thr, 64x64 output per block.
// ---------------------------------------------------------------------------
__global__ __launch_bounds__(256) void k_amat(
    const float* __restrict__ kc, const float* __restrict__ vc,
    const float* __restrict__ wgt, float* __restrict__ apart)
{
    const int tid = threadIdx.x, tx = tid & 15, ty = tid >> 4;
    const int bh = blockIdx.x, slc = blockIdx.y;
    const float* kb = kc + (size_t)bh * 65536;
    const float* vb = vc + (size_t)bh * 65536;
    const float* wb = wgt + bh*1024;

    __shared__ __align__(16) float vs[16][68];
    __shared__ __align__(16) float ks2[16][68];
    __shared__ float ww[16];
    float acc[4][4] = {};
    const float4* k4 = (const float4*)kb;
    const float4* v4 = (const float4*)vb;
    for (int j0 = slc*256; j0 < slc*256 + 256; j0 += 16) {
        if (tid < 16) ww[tid] = wb[j0 + tid];
        {
            int r = tid >> 4, c4 = tid & 15;
            *(float4*)&vs[r][c4*4]  = v4[(size_t)(j0 + r)*16 + c4];
            *(float4*)&ks2[r][c4*4] = k4[(size_t)(j0 + r)*16 + c4];
        }
        __syncthreads();
        #pragma unroll
        for (int jj = 0; jj < 16; ++jj) {
            float wj = ww[jj];
            float a[4];
            a[0] = vs[jj][ty*4+0]*wj; a[1] = vs[jj][ty*4+1]*wj;
            a[2] = vs[jj][ty*4+2]*wj; a[3] = vs[jj][ty*4+3]*wj;
            float4 b4 = *(const float4*)&ks2[jj][tx*4];
            float bb[4] = {b4.x, b4.y, b4.z, b4.w};
            #pragma unroll
            for (int ii = 0; ii < 4; ++ii)
                #pragma unroll
                for (int jc = 0; jc < 4; ++jc)
                    acc[ii][jc] += a[ii] * bb[jc];
        }
        __syncthreads();
    }
    float* ap = apart + (size_t)(slc*16 + bh) * 4096;
    #pragma unroll
    for (int i = 0; i < 4; ++i) {
        float4 o = { acc[i][0], acc[i][1], acc[i][2], acc[i][3] };
        *(float4*)&ap[(ty*4+i)*64 + tx*4] = o;
    }
}

// ---------------------------------------------------------------------------
// K6: ctxt = q @ A (summing the 4 A-partials on load), row-normalize,
// write unit vectors into [B,L,D] layout.  grid (16 lTiles, 16 bh), 256 thr.
// ---------------------------------------------------------------------------
__global__ __launch_bounds__(256) void k_ctxt(
    const float* __restrict__ q, const float* __restrict__ apart,
    float* __restrict__ u)
{
    const int tid = threadIdx.x, tx = tid & 15, ty = tid >> 4;
    const int l0 = blockIdx.x * 64;
    const int bh = blockIdx.y;
    const float* qb = q + (size_t)bh * 65536;

    __shared__ float qs[64][17];
    __shared__ __align__(16) float As[16][68];
    float acc[4][4] = {};
    const float4* q4 = (const float4*)qb;
    const float4* a4 = (const float4*)apart;
    for (int d0 = 0; d0 < 64; d0 += 16) {
        {
            int r = tid >> 2, c4 = tid & 3;
            float4 t = q4[(size_t)(l0 + r)*16 + (d0 >> 2) + c4];
            qs[r][c4*4+0]=t.x; qs[r][c4*4+1]=t.y; qs[r][c4*4+2]=t.z; qs[r][c4*4+3]=t.w;
        }
        {
            int r = tid >> 4, c4 = tid & 15;
            size_t o = (size_t)(d0 + r)*16 + c4;
            float4 t0 = a4[(size_t)(0*16 + bh)*1024 + o];
            float4 t1 = a4[(size_t)(1*16 + bh)*1024 + o];
            float4 t2 = a4[(size_t)(2*16 + bh)*1024 + o];
            float4 t3 = a4[(size_t)(3*16 + bh)*1024 + o];
            float4 t;
            t.x = t0.x+t1.x+t2.x+t3.x; t.y = t0.y+t1.y+t2.y+t3.y;
            t.z = t0.z+t1.z+t2.z+t3.z; t.w = t0.w+t1.w+t2.w+t3.w;
            *(float4*)&As[r][c4*4] = t;
        }
        __syncthreads();
        #pragma unroll
        for (int dd = 0; dd < 16; ++dd) {
            float a[4];
            a[0] = qs[ty*4+0][dd]; a[1] = qs[ty*4+1][dd];
            a[2] = qs[ty*4+2][dd]; a[3] = qs[ty*4+3][dd];
            float4 b4 = *(const float4*)&As[dd][tx*4];
            float bb[4] = {b4.x, b4.y, b4.z, b4.w};
            #pragma unroll
            for (int ii = 0; ii < 4; ++ii)
                #pragma unroll
                for (int jj = 0; jj < 4; ++jj)
                    acc[ii][jj] += a[ii] * bb[jj];
        }
        __syncthreads();
    }
    __shared__ float red[64][17];
    __shared__ float nrm[64];
    #pragma unroll
    for (int i = 0; i < 4; ++i) {
        red[ty*4+i][tx] = acc[i][0]*acc[i][0] + acc[i][1]*acc[i][1]
                        + acc[i][2]*acc[i][2] + acc[i][3]*acc[i][3];
    }
    __syncthreads();
    if (tid < 64) {
        float s = 0.0f;
        #pragma unroll
        for (int t = 0; t < 16; ++t) s += red[tid][t];
        nrm[tid] = fmaxf(sqrtf(s), 1e-5f);
    }
    __syncthreads();
    const int b = bh >> 3, hd = bh & 7;
    #pragma unroll
    for (int i = 0; i < 4; ++i) {
        int lr = ty*4 + i;
        float inv = 1.0f / nrm[lr];
        float4 o = { acc[i][0]*inv, acc[i][1]*inv, acc[i][2]*inv, acc[i][3]*inv };
        *(float4*)&u[(size_t)(b*1024 + l0 + lr)*512 + hd*64 + tx*4] = o;
    }
}

// ---------------------------------------------------------------------------
// K7: out = U[2048,512] @ wo[512,512] + wo_b.  grid (8, 32), 256 thr.
// ---------------------------------------------------------------------------
__global__ __launch_bounds__(256) void k_out(
    const float* __restrict__ uu, const float* __restrict__ wo,
    const float* __restrict__ bo, float* __restrict__ out)
{
    const int tid = threadIdx.x;
    const int tx = tid & 15, ty = tid >> 4;
    const int col0 = blockIdx.x * 64;
    const int row0 = blockIdx.y * 64;

    __shared__ float xs[64][17];
    __shared__ __align__(16) float wsb[16][68];
    float acc[4][4] = {};

    const float4* x4 = (const float4*)uu;
    const float4* w4 = (const float4*)wo;
    for (int k0 = 0; k0 < 512; k0 += 16) {
        {
            int r = tid >> 2, c4 = tid & 3;
            float4 t = x4[(size_t)(row0 + r) * 128 + (k0 >> 2) + c4];
            xs[r][c4*4+0] = t.x; xs[r][c4*4+1] = t.y;
            xs[r][c4*4+2] = t.z; xs[r][c4*4+3] = t.w;
        }
        {
            int r = tid >> 4, c4 = tid & 15;
            float4 t = w4[(size_t)(k0 + r) * 128 + (col0 >> 2) + c4];
            *(float4*)&wsb[r][c4*4] = t;
        }
        __syncthreads();
        #pragma unroll
        for (int kk = 0; kk < 16; ++kk) {
            float a[4];
            a[0] = xs[ty*4+0][kk]; a[1] = xs[ty*4+1][kk];
            a[2] = xs[ty*4+2][kk]; a[3] = xs[ty*4+3][kk];
            float4 b4 = *(const float4*)&wsb[kk][tx*4];
            float bb[4] = {b4.x, b4.y, b4.z, b4.w};
            #pragma unroll
            for (int ii = 0; ii < 4; ++ii)
                #pragma unroll
                for (int jj = 0; jj < 4; ++jj)
                    acc[ii][jj] += a[ii] * bb[jj];
        }
        __syncthreads();
    }
    const int dd = tx * 4;
    #pragma unroll
    for (int i = 0; i < 4; ++i) {
        float4 o;
        o.x = acc[i][0] + bo[col0+dd+0];
        o.y = acc[i][1] + bo[col0+dd+1];
        o.z = acc[i][2] + bo[col0+dd+2];
        o.w = acc[i][3] + bo[col0+dd+3];
        *(float4*)&out[(size_t)(row0 + ty*4 + i) * 512 + col0 + dd] = o;
    }
}

extern "C" void kernel_launch(void* const* d_in, const int* in_sizes, int n_in,
                              void* d_out, int out_size, void* d_ws, size_t ws_size,
                              hipStream_t stream)
{
    const float* x   = (const float*)d_in[0];
    const float* sb  = (const float*)d_in[1];
    const float* wq  = (const float*)d_in[2];
    const float* bq  = (const float*)d_in[3];
    const float* wk  = (const float*)d_in[4];
    const float* bk  = (const float*)d_in[5];
    const float* wv  = (const float*)d_in[6];
    const float* bv  = (const float*)d_in[7];
    const float* wo  = (const float*)d_in[8];
    const float* bo  = (const float*)d_in[9];
    const float* wg  = (const float*)d_in[10];
    const float* wgb = (const float*)d_in[11];
    float* out = (float*)d_out;
    float* ws  = (float*)d_ws;

    // workspace layout (floats)
    float* Q   = ws;                    // 1048576  [B,H,L,64]
    float* Kt  = ws + 1048576;          // 1048576  (scaled k)
    float* V   = ws + 2*1048576;        // 1048576
    float* KC  = ws + 3*1048576;        // 1048576  k_conv
    float* VC  = ws + 4*1048576;        // 1048576  v_conv
    float* GL  = ws + 5*1048576;        // 16384    gates g
    float* WGT = GL + 16384;            // 16384    w_j = g_j*c_j
    float* AP  = WGT + 16384;           // 4*65536  A partials
    float* U   = AP + 4*65536;          // 1048576  unit vectors [B,L,D]

    k_qkv <<<dim3(8, 32, 3), 256, 0, stream>>>(x, wq, bq, wk, bk, wv, bv, Q, Kt, V);
    k_conv<<<dim3(16, 32),   256, 0, stream>>>(sb, Kt, V, KC, VC);
    k_gate<<<dim3(16, 16),   256, 0, stream>>>(KC, VC, wg, wgb, GL);
    k_scan<<<dim3(16),       256, 0, stream>>>(GL, WGT);
    k_amat<<<dim3(16, 4),    256, 0, stream>>>(KC, VC, WGT, AP);
    k_ctxt<<<dim3(16, 16),   256, 0, stream>>>(Q, AP, U);
    k_out <<<dim3(8, 32),    256, 0, stream>>>(U, wo, bo, out);
}